// Round 3
// baseline (217.107 us; speedup 1.0000x reference)
//
#include <hip/hip_runtime.h>
#include <hip/hip_bf16.h>

typedef __attribute__((ext_vector_type(8))) short short8;
typedef __attribute__((ext_vector_type(4))) float f32x4;

#define EPS 1e-6f
#define NBLK 8192

static __device__ __forceinline__ short f2bf(float f) {
    unsigned u = __float_as_uint(f);
    unsigned r = (u + 0x7FFFu + ((u >> 16) & 1u)) >> 16;
    return (short)(unsigned short)r;
}

// ---- prep: bf16 relation embeds (padded to 64 rows) + per-relation const ----
__global__ void prep_kernel(const float* __restrict__ re, short* __restrict__ re_bf,
                            float* __restrict__ re_c2, int R) {
    int tid = threadIdx.x;          // 256 threads, 1 block
    int r = tid >> 2, q = tid & 3;  // r in 0..63, q = quarter of the row
    float v[32];
    if (r < R) {
        const float* p = re + (size_t)r * 128 + q * 32;
#pragma unroll
        for (int j = 0; j < 32; ++j) v[j] = p[j];
    } else {
#pragma unroll
        for (int j = 0; j < 32; ++j) v[j] = 0.f;
    }
    float ssq = 0.f, sum = 0.f;
#pragma unroll
    for (int j = 0; j < 32; ++j) { ssq = fmaf(v[j], v[j], ssq); sum += v[j]; }
    ssq += __shfl_xor(ssq, 1); ssq += __shfl_xor(ssq, 2);
    sum += __shfl_xor(sum, 1); sum += __shfl_xor(sum, 2);
    short* o = re_bf + r * 128 + q * 32;
#pragma unroll
    for (int j = 0; j < 32; ++j) o[j] = f2bf(v[j]);
    if (q == 0) re_c2[r] = (r < R) ? (ssq - 2.f * EPS * sum) : -1e30f;
}

// ---- main: 1 wave/block; global_load_lds coalesced staging + swizzled ds_read ----
__global__ __launch_bounds__(64) void loss_main(
    const float* __restrict__ mo, const float* __restrict__ tg,
    const short* __restrict__ re_bf, const float* __restrict__ re_c2,
    float* __restrict__ partials, int nrows) {
    __shared__ char lds[32768] __attribute__((aligned(16)));  // 2 x (8KB mo | 8KB tg)
    const int lane = threadIdx.x;
    const int col16 = lane & 15;   // mo-row within tile / C col
    const int kg = lane >> 4;      // k-group 0..3
    const int ko = kg * 8;

    // relation A-fragments + constants -> registers (one-time global loads)
    short8 bfrag[4][4];
    float rc[4][4];
#pragma unroll
    for (int rt = 0; rt < 4; ++rt) {
#pragma unroll
        for (int s = 0; s < 4; ++s)
            bfrag[rt][s] = *reinterpret_cast<const short8*>(
                re_bf + (rt * 16 + col16) * 128 + s * 32 + ko);
#pragma unroll
        for (int reg = 0; reg < 4; ++reg)
            rc[rt][reg] = re_c2[rt * 16 + kg * 4 + reg];
    }

    const int NT = nrows >> 4;
    const int stride = gridDim.x;
    const int t0 = blockIdx.x;
    float corr_acc = 0.f, inc_acc = 0.f;

    // ds_read side: lane's linear in-tile byte offset + XOR swizzle
    const int roff = col16 * 512 + kg * 32;
    const int swz  = (col16 & 7) << 4;

    // stage tile t (mo 8KB + tg 8KB) into buffer p.
    // global source pre-swizzled (byte ^= ((byte>>9 &7)<<4)) so LDS-linear dest
    // holds the swizzled image; per-instruction global footprint is a
    // contiguous, fully-covered 1KB (perfect line coalescing).
    auto stage = [&](int t, int p) {
        const char* mo_b = (const char*)mo + (size_t)t * 8192;
        const char* tg_b = (const char*)tg + (size_t)t * 8192;
        char* lbase = (char*)lds + p * 16384;
#pragma unroll
        for (int j = 0; j < 8; ++j) {
            int lin = j * 1024 + lane * 16;
            int g = lin ^ (((lin >> 9) & 7) << 4);
            __builtin_amdgcn_global_load_lds(
                (const __attribute__((address_space(1))) void*)(mo_b + g),
                (__attribute__((address_space(3))) void*)(lbase + j * 1024), 16, 0, 0);
            __builtin_amdgcn_global_load_lds(
                (const __attribute__((address_space(1))) void*)(tg_b + g),
                (__attribute__((address_space(3))) void*)(lbase + 8192 + j * 1024), 16, 0, 0);
        }
    };

    if (t0 < NT) {
        // drain the one-time register loads before manual vmcnt counting starts
        asm volatile("s_waitcnt vmcnt(0)" ::: "memory");
        __builtin_amdgcn_sched_barrier(0);
        stage(t0, 0);
        if (t0 + stride < NT) stage(t0 + stride, 1);
        int p = 0;

        for (int t = t0; t < NT; t += stride) {
            const bool nxt   = (t + stride) < NT;
            const bool more2 = (t + 2 * stride) < NT;
            if (nxt) { asm volatile("s_waitcnt vmcnt(16)" ::: "memory"); }
            else     { asm volatile("s_waitcnt vmcnt(0)"  ::: "memory"); }
            __builtin_amdgcn_sched_barrier(0);

            const char* lb = (const char*)lds + p * 16384;
            alignas(16) float x[32];
            alignas(16) float tv[32];
#pragma unroll
            for (int s = 0; s < 4; ++s) {
                *(f32x4*)(x + s * 8)      = *(const f32x4*)(lb + ((roff + s * 128)      ^ swz));
                *(f32x4*)(x + s * 8 + 4)  = *(const f32x4*)(lb + ((roff + s * 128 + 16) ^ swz));
            }
#pragma unroll
            for (int s = 0; s < 4; ++s) {
                *(f32x4*)(tv + s * 8)     = *(const f32x4*)(lb + 8192 + ((roff + s * 128)      ^ swz));
                *(f32x4*)(tv + s * 8 + 4) = *(const f32x4*)(lb + 8192 + ((roff + s * 128 + 16) ^ swz));
            }
            // reads retired -> safe to overwrite this buffer with tile t+2
            asm volatile("s_waitcnt lgkmcnt(0)" ::: "memory");
            __builtin_amdgcn_sched_barrier(0);
            if (more2) stage(t + 2 * stride, p);

            // ---- row stats ----
            float ssq = 0.f, sum = 0.f;
#pragma unroll
            for (int j = 0; j < 32; ++j) { ssq = fmaf(x[j], x[j], ssq); sum += x[j]; }
            float xt = 0.f, tsq = 0.f, tsum = 0.f;
#pragma unroll
            for (int j = 0; j < 32; ++j) {
                xt  = fmaf(x[j], tv[j], xt);
                tsq = fmaf(tv[j], tv[j], tsq);
                tsum += tv[j];
            }
            ssq  += __shfl_xor(ssq, 16);  ssq  += __shfl_xor(ssq, 32);
            sum  += __shfl_xor(sum, 16);  sum  += __shfl_xor(sum, 32);
            xt   += __shfl_xor(xt, 16);   xt   += __shfl_xor(xt, 32);
            tsq  += __shfl_xor(tsq, 16);  tsq  += __shfl_xor(tsq, 32);
            tsum += __shfl_xor(tsum, 16); tsum += __shfl_xor(tsum, 32);

            float rnorm  = 1.0f / fmaxf(sqrtf(ssq), 1e-12f);
            float mo_sq  = ssq * rnorm * rnorm;
            float mo_sum = sum * rnorm;
            float mconst = fmaf(2.f * EPS, mo_sum, mo_sq) + 128.f * EPS * EPS;

            // correct term via expansion: ||m_hat - t + eps||^2
            float cs = mconst + tsq - 2.f * EPS * tsum - 2.f * rnorm * xt;
            if (kg == 0) corr_acc += sqrtf(fmaxf(cs, 0.f));

            // pack normalized mo into B-fragment
            short8 afrag[4];
#pragma unroll
            for (int s = 0; s < 4; ++s)
#pragma unroll
                for (int j = 0; j < 8; ++j)
                    afrag[s][j] = __builtin_bit_cast(short, __float2bfloat16(x[s * 8 + j] * rnorm));

            // MFMA: A = relations (reg-resident), B = mo
            // C[relation][mo_row]: col = col16 = mo row, row = rt*16 + kg*4 + reg
            float vmax = -1e30f;
#pragma unroll
            for (int rt = 0; rt < 4; ++rt) {
                f32x4 acc = {0.f, 0.f, 0.f, 0.f};
#pragma unroll
                for (int s = 0; s < 4; ++s)
                    acc = __builtin_amdgcn_mfma_f32_16x16x32_bf16(
                        bfrag[rt][s], afrag[s], acc, 0, 0, 0);
#pragma unroll
                for (int reg = 0; reg < 4; ++reg) {
                    float d2 = mconst + rc[rt][reg] - 2.f * acc[reg];
                    vmax = fmaxf(vmax, d2);
                }
            }
            vmax = fmaxf(vmax, __shfl_xor(vmax, 16));
            vmax = fmaxf(vmax, __shfl_xor(vmax, 32));
            if (kg == 0) inc_acc += sqrtf(fmaxf(vmax, 0.f));

            p ^= 1;
        }
    }

    // wave-level reduce (nonzero only on lanes 0..15)
#pragma unroll
    for (int m = 1; m < 16; m <<= 1) {
        corr_acc += __shfl_xor(corr_acc, m);
        inc_acc  += __shfl_xor(inc_acc, m);
    }
    if (lane == 0) {
        partials[blockIdx.x * 2]     = corr_acc;
        partials[blockIdx.x * 2 + 1] = inc_acc;
    }
}

// ---- final: reduce block partials to the scalar loss ----
__global__ void final_kernel(const float* __restrict__ partials, float* __restrict__ out, int nb) {
    __shared__ float rc_[256];
    __shared__ float ri_[256];
    int tid = threadIdx.x;
    float c = 0.f, ic = 0.f;
    for (int i = tid; i < nb; i += 256) { c += partials[2 * i]; ic += partials[2 * i + 1]; }
    rc_[tid] = c; ri_[tid] = ic;
    __syncthreads();
    for (int s = 128; s > 0; s >>= 1) {
        if (tid < s) { rc_[tid] += rc_[tid + s]; ri_[tid] += ri_[tid + s]; }
        __syncthreads();
    }
    if (tid == 0) out[0] = rc_[0] + 1e-4f * (1.f - ri_[0]);
}

extern "C" void kernel_launch(void* const* d_in, const int* in_sizes, int n_in,
                              void* d_out, int out_size, void* d_ws, size_t ws_size,
                              hipStream_t stream) {
    const float* mo = (const float*)d_in[0];
    const float* tg = (const float*)d_in[1];
    const float* re = (const float*)d_in[2];
    const int D = 128;
    const int nrows = in_sizes[0] / D;
    const int R = in_sizes[2] / D;

    char* ws = (char*)d_ws;
    short* re_bf    = (short*)ws;            // 64*128*2 = 16384 B
    float* re_c2    = (float*)(ws + 16384);  // 64*4 = 256 B
    float* partials = (float*)(ws + 16896);  // NBLK*2*4 = 65536 B

    prep_kernel<<<1, 256, 0, stream>>>(re, re_bf, re_c2, R);
    loss_main<<<NBLK, 64, 0, stream>>>(mo, tg, re_bf, re_c2, partials, nrows);
    final_kernel<<<1, 256, 0, stream>>>(partials, (float*)d_out, NBLK);
}